// Round 3
// baseline (308.564 us; speedup 1.0000x reference)
//
#include <hip/hip_runtime.h>
#include <hip/hip_bf16.h>

// Problem: B=4, S=8192, D_IN=1024, D_OUT=1024. M = B*S = 32768 rows.
// out[m][o] = (s * alpha) * sum_k qx[m][k] * qw[o][k]   (exact int32 dot)
// Determinism: f64 partials + f64/int atomics for scalar reductions.
//
// R4 = R3 with the nontemporal-load compile fix (ext_vector_type f32x4
// instead of HIP_vector_type float4 — builtin requires scalar/ext-vector ptr).
//  - K1: w_sum blocks dispatched FIRST (0..255) so Sum|w| overlaps under the
//    ln-stats stream instead of running in the kernel tail.
//  - K1/K2: row loops unrolled 4x (more outstanding loads -> latency hiding).
//  - GEMM: nontemporal C stores (C is write-once dead data; keep qx/qw L3-hot).
//  - K2: nontemporal x/w loads (dead after K2; don't evict qx from L3).
//  - GEMM 8-phase counted-vmcnt schedule unchanged (verified R2).

#define M_ROWS   32768
#define D_IN     1024
#define D_OUT    1024
#define W_ELEMS  (1024*1024)

typedef __attribute__((ext_vector_type(4))) int   int4v;
typedef __attribute__((ext_vector_type(4))) float f32x4;

// ---------------- workspace layout (bytes) ----------------
// @0  : u32 absmax_bits
// @4  : u32 kept_cnt
// @8  : f64 sumw
// @16 : f64 kept_sum
// [1024]    : mu   [32768] f32  (128 KB)
// [132096]  : rstd [32768] f32  (128 KB)
// [263168]  : qw   [1024*1024] i8 (1 MB)
// [1311744] : qx   [32768*1024] i8 (32 MB)

// ---------------- K1: sum|w| (blocks 0..255) || LN stats+absmax (256..1279) --
__global__ __launch_bounds__(256) void ln_stats_wsum_kernel(
    const float* __restrict__ x, const float* __restrict__ gamma,
    const float* __restrict__ beta, float* __restrict__ mu_out,
    float* __restrict__ rstd_out, unsigned int* __restrict__ absmax_bits,
    const float* __restrict__ w, double* __restrict__ sumw) {
  __shared__ float wm[4];
  __shared__ double ls[4];
  int t = threadIdx.x;
  int wave = t >> 6, lane = t & 63;

  if (blockIdx.x >= 256) {
    int wgid = (blockIdx.x - 256) * 4 + wave;   // 0..4095
    float4 g[4], b[4];
    #pragma unroll
    for (int k = 0; k < 4; k++) {
      g[k] = ((const float4*)gamma)[lane + 64 * k];
      b[k] = ((const float4*)beta )[lane + 64 * k];
    }
    float amax = 0.0f;
    #pragma unroll 4
    for (int i = 0; i < 8; i++) {
      int row = wgid + 4096 * i;
      const float4* xr = (const float4*)(x + (size_t)row * D_IN);
      float4 v[4];
      #pragma unroll
      for (int k = 0; k < 4; k++) v[k] = xr[lane + 64 * k];
      float s = 0.0f, sq = 0.0f;
      #pragma unroll
      for (int k = 0; k < 4; k++) {
        s  += v[k].x + v[k].y + v[k].z + v[k].w;
        sq += v[k].x*v[k].x + v[k].y*v[k].y + v[k].z*v[k].z + v[k].w*v[k].w;
      }
      #pragma unroll
      for (int off = 1; off < 64; off <<= 1) {
        s  += __shfl_xor(s,  off, 64);
        sq += __shfl_xor(sq, off, 64);
      }
      float mu   = s * (1.0f / D_IN);
      float var  = sq * (1.0f / D_IN) - mu * mu;
      float rstd = rsqrtf(var + 1e-5f);
      if (lane == 0) { mu_out[row] = mu; rstd_out[row] = rstd; }
      #pragma unroll
      for (int k = 0; k < 4; k++) {
        float nx = (v[k].x - mu) * rstd * g[k].x + b[k].x;
        float ny = (v[k].y - mu) * rstd * g[k].y + b[k].y;
        float nz = (v[k].z - mu) * rstd * g[k].z + b[k].z;
        float nw = (v[k].w - mu) * rstd * g[k].w + b[k].w;
        amax = fmaxf(amax, fmaxf(fmaxf(fabsf(nx), fabsf(ny)),
                                 fmaxf(fabsf(nz), fabsf(nw))));
      }
    }
    #pragma unroll
    for (int off = 1; off < 64; off <<= 1)
      amax = fmaxf(amax, __shfl_xor(amax, off, 64));
    if (lane == 0) wm[wave] = amax;
    __syncthreads();
    if (t == 0) {
      float m = fmaxf(fmaxf(wm[0], wm[1]), fmaxf(wm[2], wm[3]));
      atomicMax(absmax_bits, __float_as_uint(m));  // m>=0: uint order == float order
    }
  } else {
    int base = blockIdx.x * 1024 + t;
    double s = 0.0;
    #pragma unroll
    for (int j = 0; j < 4; j++) {
      float4 v = ((const float4*)w)[base + 256 * j];
      s += (double)fabsf(v.x) + (double)fabsf(v.y) +
           (double)fabsf(v.z) + (double)fabsf(v.w);
    }
    #pragma unroll
    for (int off = 1; off < 64; off <<= 1) s += __shfl_xor(s, off, 64);
    if (lane == 0) ls[wave] = s;
    __syncthreads();
    if (t == 0) atomicAdd(sumw, ls[0] + ls[1] + ls[2] + ls[3]);
  }
}

// ---------------- K2: ternary-quantize weights || quantize activations ----
// blocks 0..255: w_quant; blocks 256..2303: act_quant (16 rows each)
__global__ __launch_bounds__(256) void wquant_actquant_kernel(
    const float* __restrict__ w, const double* __restrict__ sumw,
    signed char* __restrict__ qw, double* __restrict__ kept_sum,
    unsigned int* __restrict__ kept_cnt,
    const float* __restrict__ x, const float* __restrict__ gamma,
    const float* __restrict__ beta, const float* __restrict__ mu_arr,
    const float* __restrict__ rstd_arr,
    const unsigned int* __restrict__ absmax_bits, signed char* __restrict__ qx) {
  __shared__ double lss[4];
  __shared__ int    lcc[4];
  int t = threadIdx.x;

  if (blockIdx.x < 256) {
    double delta = 0.7 * (*sumw) * (1.0 / (double)W_ELEMS);
    int base = blockIdx.x * 1024 + t;
    double ks = 0.0;
    int kc = 0;
    #pragma unroll
    for (int j = 0; j < 4; j++) {
      f32x4 v = __builtin_nontemporal_load(((const f32x4*)w) + base + 256 * j);
      char4 q;
      {
        double a = (double)fabsf(v.x); bool m = a > delta;
        q.x = m ? (v.x > 0.0f ? 1 : -1) : 0; if (m) { ks += a; kc++; }
      }
      {
        double a = (double)fabsf(v.y); bool m = a > delta;
        q.y = m ? (v.y > 0.0f ? 1 : -1) : 0; if (m) { ks += a; kc++; }
      }
      {
        double a = (double)fabsf(v.z); bool m = a > delta;
        q.z = m ? (v.z > 0.0f ? 1 : -1) : 0; if (m) { ks += a; kc++; }
      }
      {
        double a = (double)fabsf(v.w); bool m = a > delta;
        q.w = m ? (v.w > 0.0f ? 1 : -1) : 0; if (m) { ks += a; kc++; }
      }
      ((char4*)qw)[base + 256 * j] = q;
    }
    #pragma unroll
    for (int off = 1; off < 64; off <<= 1) {
      ks += __shfl_xor(ks, off, 64);
      kc += __shfl_xor(kc, off, 64);
    }
    int wave = t >> 6, lane = t & 63;
    if (lane == 0) { lss[wave] = ks; lcc[wave] = kc; }
    __syncthreads();
    if (t == 0) {
      atomicAdd(kept_sum, lss[0] + lss[1] + lss[2] + lss[3]);
      atomicAdd(kept_cnt, (unsigned int)(lcc[0] + lcc[1] + lcc[2] + lcc[3]));
    }
  } else {
    float am = __uint_as_float(*absmax_bits);
    float scale = fmaxf(am, 1e-8f) / 127.0f;
    float4 g = ((const float4*)gamma)[t];
    float4 b = ((const float4*)beta)[t];
    int bid2 = blockIdx.x - 256;
    #pragma unroll 4
    for (int i = 0; i < 16; i++) {
      int row = bid2 * 16 + i;
      float mu = mu_arr[row], rstd = rstd_arr[row];
      f32x4 v = __builtin_nontemporal_load(
          ((const f32x4*)(x + (size_t)row * D_IN)) + t);
      float nx = ((v.x - mu) * rstd * g.x + b.x) / scale;
      float ny = ((v.y - mu) * rstd * g.y + b.y) / scale;
      float nz = ((v.z - mu) * rstd * g.z + b.z) / scale;
      float nw = ((v.w - mu) * rstd * g.w + b.w) / scale;
      char4 q;
      q.x = (signed char)(int)rintf(fminf(fmaxf(nx, -127.0f), 127.0f));
      q.y = (signed char)(int)rintf(fminf(fmaxf(ny, -127.0f), 127.0f));
      q.z = (signed char)(int)rintf(fminf(fmaxf(nz, -127.0f), 127.0f));
      q.w = (signed char)(int)rintf(fminf(fmaxf(nw, -127.0f), 127.0f));
      ((char4*)(qx + (size_t)row * D_IN))[t] = q;
    }
  }
}

// ---------------- K5: int8 GEMM, 256x256 tile, 8-phase counted-vmcnt --------
// m201-style schedule: 8 waves (2M x 4N), per-wave out 128x64, BK=128 i8.
// LDS 128 KiB: A: 2buf x 2half x [128 rows][128B]; B same at +64KiB.
// st_16x32 swizzle: linear global_load_lds dest + inverse-swizzled global
// SOURCE + swizzled READ. Stage slot-reuse: a slot is restaged only after the
// phase whose end-barrier retires its last ds_read.
//   p0: B(tO)h1 + A(tO)h1        p4: A(tE+2)h1
//   p2: B(tE+2)h0                p6: B(tO+2)h0
//   p3: B(tE+2)h1 + A(tE+2)h0    p7: A(tO+2)h0
// Waits: end-p3 vmcnt(6) -> tO complete; end-p7 vmcnt(4) -> tE+2 complete.
// Never drains to 0 in the main loop.

__device__ __forceinline__ void stage16(const signed char* src, signed char* dst) {
  __builtin_amdgcn_global_load_lds(
      (const __attribute__((address_space(1))) unsigned int*)src,
      (__attribute__((address_space(3))) unsigned int*)dst, 16, 0, 0);
}

#define BAR()   __builtin_amdgcn_s_barrier()
#define BARS()  { __builtin_amdgcn_s_barrier(); __builtin_amdgcn_sched_barrier(0); }
#define LGKM0() { asm volatile("s_waitcnt lgkmcnt(0)" ::: "memory"); __builtin_amdgcn_sched_barrier(0); }
#define VMW(N)  { asm volatile("s_waitcnt vmcnt(" #N ")" ::: "memory"); __builtin_amdgcn_sched_barrier(0); }

#define STAGE_A(BUF, HALF, KB) { \
  signed char* d_ = ldsA + (((BUF)*2 + (HALF)) << 14) + (tid << 4); \
  const signed char* s_ = Asrc + (size_t)(HALF) * (128 * D_IN) + (KB); \
  stage16(s_, d_); stage16(s_ + 64 * D_IN, d_ + 8192); }

#define STAGE_B(BUF, HALF, KB) { \
  signed char* d_ = ldsB + (((BUF)*2 + (HALF)) << 14) + (tid << 4); \
  const signed char* s_ = Bsrc + (size_t)(HALF) * (128 * D_IN) + (KB); \
  stage16(s_, d_); stage16(s_ + 64 * D_IN, d_ + 8192); }

#define LOAD_A(P, RH) { _Pragma("unroll") \
  for (int f_ = 0; f_ < 4; f_++) { \
    const signed char* rp_ = (P) + (((RH)*64 + f_*16 + lrow) << 7); \
    a[f_][0] = *(const int4v*)(rp_ + kA0); \
    a[f_][1] = *(const int4v*)(rp_ + kA1); } }

#define LOAD_B(P, CH) { _Pragma("unroll") \
  for (int g_ = 0; g_ < 2; g_++) { \
    const signed char* rp_ = (P) + ((bro + (CH)*32 + g_*16 + lrow) << 7); \
    b[CH][g_][0] = *(const int4v*)(rp_ + kA0); \
    b[CH][g_][1] = *(const int4v*)(rp_ + kA1); } }

#define MFMA_Q(RH, CH) { _Pragma("unroll") \
  for (int f_ = 0; f_ < 4; f_++) { _Pragma("unroll") \
    for (int g_ = 0; g_ < 2; g_++) { \
      acc[(RH)*4+f_][(CH)*2+g_] = __builtin_amdgcn_mfma_i32_16x16x64_i8( \
          a[f_][0], b[CH][g_][0], acc[(RH)*4+f_][(CH)*2+g_], 0, 0, 0); \
      acc[(RH)*4+f_][(CH)*2+g_] = __builtin_amdgcn_mfma_i32_16x16x64_i8( \
          a[f_][1], b[CH][g_][1], acc[(RH)*4+f_][(CH)*2+g_], 0, 0, 0); } } }

#define KITER(FULL, koO, koE2, koO2) \
  /* p0: Q0 of tE */ \
  LOAD_A(pA0, 0); LOAD_B(pB0, 0); \
  STAGE_B(1, 1, koO); STAGE_A(1, 1, koO); \
  asm volatile("s_waitcnt lgkmcnt(8)" ::: "memory"); \
  BAR(); LGKM0(); \
  __builtin_amdgcn_s_setprio(1); MFMA_Q(0, 0); __builtin_amdgcn_s_setprio(0); BARS(); \
  /* p1: Q1 of tE */ \
  LOAD_B(pB0, 1); BAR(); LGKM0(); \
  __builtin_amdgcn_s_setprio(1); MFMA_Q(0, 1); __builtin_amdgcn_s_setprio(0); BARS(); \
  /* p2: Q2 of tE */ \
  LOAD_A(pA0, 1); if (FULL) { STAGE_B(0, 0, koE2); } BAR(); LGKM0(); \
  __builtin_amdgcn_s_setprio(1); MFMA_Q(1, 0); __builtin_amdgcn_s_setprio(0); BARS(); \
  /* p3: Q3 of tE (reg-only) */ \
  if (FULL) { STAGE_B(0, 1, koE2); STAGE_A(0, 0, koE2); } BAR(); \
  __builtin_amdgcn_s_setprio(1); MFMA_Q(1, 1); __builtin_amdgcn_s_setprio(0); \
  if (FULL) { VMW(6); } else { VMW(0); } BARS(); \
  /* p4: Q0 of tO */ \
  LOAD_A(pA1, 0); LOAD_B(pB1, 0); if (FULL) { STAGE_A(0, 1, koE2); } \
  asm volatile("s_waitcnt lgkmcnt(8)" ::: "memory"); \
  BAR(); LGKM0(); \
  __builtin_amdgcn_s_setprio(1); MFMA_Q(0, 0); __builtin_amdgcn_s_setprio(0); BARS(); \
  /* p5: Q1 of tO */ \
  LOAD_B(pB1, 1); BAR(); LGKM0(); \
  __builtin_amdgcn_s_setprio(1); MFMA_Q(0, 1); __builtin_amdgcn_s_setprio(0); BARS(); \
  /* p6: Q2 of tO */ \
  LOAD_A(pA1, 1); if (FULL) { STAGE_B(1, 0, koO2); } BAR(); LGKM0(); \
  __builtin_amdgcn_s_setprio(1); MFMA_Q(1, 0); __builtin_amdgcn_s_setprio(0); BARS(); \
  /* p7: Q3 of tO (reg-only) */ \
  if (FULL) { STAGE_A(1, 0, koO2); } BAR(); \
  __builtin_amdgcn_s_setprio(1); MFMA_Q(1, 1); __builtin_amdgcn_s_setprio(0); \
  if (FULL) { VMW(4); } BARS();

__global__ __launch_bounds__(512, 2) void gemm_i8_256_kernel(
    const signed char* __restrict__ A,   // qx [32768][1024]
    const signed char* __restrict__ B,   // qw [1024][1024] (row = out feature)
    float* __restrict__ C,               // [32768][1024]
    const unsigned int* __restrict__ absmax_bits,
    const double* __restrict__ kept_sum, const unsigned int* __restrict__ kept_cnt) {
  extern __shared__ __align__(16) signed char lds[];   // 131072 B
  signed char* ldsA = lds;
  signed char* ldsB = lds + 65536;

  const int tid = threadIdx.x;          // 0..511
  const int lane = tid & 63;
  const int wid = tid >> 6;             // 0..7
  const int wr = wid >> 2;              // 0..1 (M)
  const int wc = wid & 3;               // 0..3 (N)

  // XCD-aware bijective swizzle (nwg=512, 512%8==0)
  int wg = ((blockIdx.x & 7) << 6) + (blockIdx.x >> 3);
  const int m0 = (wg >> 2) << 8;        // 128 m-blocks
  const int n0 = (wg & 3) << 8;         // 4 n-blocks

  // Scalar factors: load + DRAIN before any staging so vmcnt counting stays
  // exact in the pipelined loop.
  float am = __uint_as_float(*absmax_bits);
  double ksum = *kept_sum;
  unsigned int kcnt = *kept_cnt;
  asm volatile("s_waitcnt vmcnt(0) lgkmcnt(0)" ::: "memory");
  __builtin_amdgcn_sched_barrier(0);
  double alpha = ksum / (double)max(kcnt, 1u);
  float fscale = (float)(((double)fmaxf(am, 1e-8f) / 127.0) * alpha);

  // Staging geometry: linear LDS dest (o = tid*16, +8192), source address
  // pre-swizzled with the same involution the reads apply.
  int so = (tid << 4) ^ (((tid >> 5) & 1) << 5);
  int r0 = so >> 7, c0 = so & 127;
  const signed char* Asrc = A + (size_t)(m0 + r0) * D_IN + c0;
  const signed char* Bsrc = B + (size_t)(n0 + r0) * D_IN + c0;

  // Read geometry: lane holds A/B row (lane&15), 16B k-chunk (lane>>4).
  const int lrow = lane & 15;
  const int kA0 = ((lane >> 4) << 4) ^ (((lrow >> 2) & 1) << 5);
  const int kA1 = 64 + kA0;
  const int bro = (wc & 1) << 6;        // B row base within its half
  const signed char* pA0 = ldsA + (wr << 14);          // buf0, A half = wr
  const signed char* pA1 = pA0 + 32768;                // buf1
  const signed char* pB0 = ldsB + ((wc >> 1) << 14);   // buf0, B half = wc>>1
  const signed char* pB1 = pB0 + 32768;                // buf1

  int4v acc[8][4] = {};
  int4v a[4][2];
  int4v b[2][2][2];

  // Prologue: tile0 complete (4 halves) + tile1 h0s; leave 4 loads in flight.
  STAGE_B(0, 0, 0); STAGE_B(0, 1, 0);
  STAGE_A(0, 0, 0); STAGE_A(0, 1, 0);
  STAGE_B(1, 0, 128); STAGE_A(1, 0, 128);
  VMW(4); BARS();

  for (int i = 0; i < 3; i++) {
    int koO  = (2 * i + 1) * 128;
    int koE2 = (2 * i + 2) * 128;
    int koO2 = (2 * i + 3) * 128;
    KITER(1, koO, koE2, koO2)
  }
  { // tail: tiles 6,7; only p0 stages (tile7 h1s); drain fully at end-p3.
    int koO = 7 * 128;
    KITER(0, koO, 0, 0)
  }

  // Epilogue: nontemporal C stores (write-once stream; keep qx/qw in L3).
  const int crow0 = m0 + (wr << 7) + ((lane >> 4) << 2);
  const int ccol0 = n0 + (wc << 6) + (lane & 15);
  #pragma unroll
  for (int rf = 0; rf < 8; rf++)
    #pragma unroll
    for (int cf = 0; cf < 4; cf++)
      #pragma unroll
      for (int rr = 0; rr < 4; rr++) {
        int row = crow0 + rf * 16 + rr;
        __builtin_nontemporal_store((float)acc[rf][cf][rr] * fscale,
                                    &C[(size_t)row * D_OUT + ccol0 + cf * 16]);
      }
}

extern "C" void kernel_launch(void* const* d_in, const int* in_sizes, int n_in,
                              void* d_out, int out_size, void* d_ws, size_t ws_size,
                              hipStream_t stream) {
  const float* x     = (const float*)d_in[0];
  const float* w     = (const float*)d_in[1];
  const float* gamma = (const float*)d_in[2];
  const float* beta  = (const float*)d_in[3];
  float* out = (float*)d_out;

  char* ws = (char*)d_ws;
  unsigned int* absmax_bits = (unsigned int*)ws;        // @0
  unsigned int* kept_cnt    = (unsigned int*)(ws + 4);  // @4
  double* sumw     = (double*)(ws + 8);                 // @8
  double* kept_sum = (double*)(ws + 16);                // @16
  float* mu   = (float*)(ws + 1024);
  float* rstd = (float*)(ws + 132096);
  signed char* qw = (signed char*)(ws + 263168);
  signed char* qx = (signed char*)(ws + 1311744);

  hipMemsetAsync(d_ws, 0, 64, stream);

  ln_stats_wsum_kernel<<<1280, 256, 0, stream>>>(x, gamma, beta, mu, rstd,
                                                 absmax_bits, w, sumw);
  wquant_actquant_kernel<<<2304, 256, 0, stream>>>(w, sumw, qw, kept_sum, kept_cnt,
                                                   x, gamma, beta, mu, rstd,
                                                   absmax_bits, qx);
  gemm_i8_256_kernel<<<512, 512, 131072, stream>>>(qx, qw, out, absmax_bits,
                                                   kept_sum, kept_cnt);
}

// Round 4
// 293.944 us; speedup vs baseline: 1.0497x; 1.0497x over previous
//
#include <hip/hip_runtime.h>
#include <hip/hip_bf16.h>

// Problem: B=4, S=8192, D_IN=1024, D_OUT=1024. M = B*S = 32768 rows.
// out[m][o] = (s * alpha) * sum_k qx[m][k] * qw[o][k]   (exact int32 dot)
//
// R5: revert R3 regressions (nt C-stores, unroll-4, nt loads -> back to R1's
// 301.6us config), keep w_sum-first ordering, and REMOVE the memset dispatch:
// all scalar reductions now go through per-block partial arrays reduced in
// FIXED ORDER by consumer kernels (bitwise deterministic, no atomics, no
// zero-init needed). 4 graph nodes -> 3.

#define M_ROWS   32768
#define D_IN     1024
#define D_OUT    1024
#define W_ELEMS  (1024*1024)

typedef __attribute__((ext_vector_type(4))) int int4v;

// ---------------- workspace layout (bytes) ----------------
// @256    : f64 wsum_part[256]   (K1 w-blocks -> K2 w-quant blocks)
// @4096   : f32 amax_part[1024]  (K1 ln-blocks -> K2 act blocks, GEMM)
// @8192   : f64 ks_part[256]     (K2 w-quant blocks -> GEMM)
// @10240  : i32 kc_part[256]     (K2 w-quant blocks -> GEMM)
// @16384  : f32 mu[32768]    (128 KB)
// @147456 : f32 rstd[32768]  (128 KB)
// @278528 : i8  qw[1024*1024] (1 MB)
// @1327104: i8  qx[32768*1024] (32 MB)
// No memset: every cell is written before it is read (enforced by kernel
// boundaries), so poison garbage never flows into results.

// ---------------- K1: sum|w| partials (blocks 0..255) ||
//                      LN stats + absmax partials (blocks 256..1279) --------
__global__ __launch_bounds__(256) void ln_stats_wsum_kernel(
    const float* __restrict__ x, const float* __restrict__ gamma,
    const float* __restrict__ beta, float* __restrict__ mu_out,
    float* __restrict__ rstd_out, float* __restrict__ amax_part,
    const float* __restrict__ w, double* __restrict__ wsum_part) {
  __shared__ float wm[4];
  __shared__ double ls[4];
  int t = threadIdx.x;
  int wave = t >> 6, lane = t & 63;

  if (blockIdx.x >= 256) {
    int bln = blockIdx.x - 256;          // 0..1023
    int wgid = bln * 4 + wave;           // 0..4095
    float4 g[4], b[4];
    #pragma unroll
    for (int k = 0; k < 4; k++) {
      g[k] = ((const float4*)gamma)[lane + 64 * k];
      b[k] = ((const float4*)beta )[lane + 64 * k];
    }
    float amax = 0.0f;
    #pragma unroll 2
    for (int i = 0; i < 8; i++) {
      int row = wgid + 4096 * i;
      const float4* xr = (const float4*)(x + (size_t)row * D_IN);
      float4 v[4];
      #pragma unroll
      for (int k = 0; k < 4; k++) v[k] = xr[lane + 64 * k];
      float s = 0.0f, sq = 0.0f;
      #pragma unroll
      for (int k = 0; k < 4; k++) {
        s  += v[k].x + v[k].y + v[k].z + v[k].w;
        sq += v[k].x*v[k].x + v[k].y*v[k].y + v[k].z*v[k].z + v[k].w*v[k].w;
      }
      #pragma unroll
      for (int off = 1; off < 64; off <<= 1) {
        s  += __shfl_xor(s,  off, 64);
        sq += __shfl_xor(sq, off, 64);
      }
      float mu   = s * (1.0f / D_IN);
      float var  = sq * (1.0f / D_IN) - mu * mu;
      float rstd = rsqrtf(var + 1e-5f);
      if (lane == 0) { mu_out[row] = mu; rstd_out[row] = rstd; }
      #pragma unroll
      for (int k = 0; k < 4; k++) {
        float nx = (v[k].x - mu) * rstd * g[k].x + b[k].x;
        float ny = (v[k].y - mu) * rstd * g[k].y + b[k].y;
        float nz = (v[k].z - mu) * rstd * g[k].z + b[k].z;
        float nw = (v[k].w - mu) * rstd * g[k].w + b[k].w;
        amax = fmaxf(amax, fmaxf(fmaxf(fabsf(nx), fabsf(ny)),
                                 fmaxf(fabsf(nz), fabsf(nw))));
      }
    }
    #pragma unroll
    for (int off = 1; off < 64; off <<= 1)
      amax = fmaxf(amax, __shfl_xor(amax, off, 64));
    if (lane == 0) wm[wave] = amax;
    __syncthreads();
    if (t == 0)
      amax_part[bln] = fmaxf(fmaxf(wm[0], wm[1]), fmaxf(wm[2], wm[3]));
  } else {
    int base = blockIdx.x * 1024 + t;
    double s = 0.0;
    #pragma unroll
    for (int j = 0; j < 4; j++) {
      float4 v = ((const float4*)w)[base + 256 * j];
      s += (double)fabsf(v.x) + (double)fabsf(v.y) +
           (double)fabsf(v.z) + (double)fabsf(v.w);
    }
    #pragma unroll
    for (int off = 1; off < 64; off <<= 1) s += __shfl_xor(s, off, 64);
    if (lane == 0) ls[wave] = s;
    __syncthreads();
    if (t == 0) wsum_part[blockIdx.x] = ((ls[0] + ls[1]) + ls[2]) + ls[3];
  }
}

// ---------------- K2: w-quant (0..255) || act-quant (256..2303) -------------
__global__ __launch_bounds__(256) void wquant_actquant_kernel(
    const float* __restrict__ w, const double* __restrict__ wsum_part,
    signed char* __restrict__ qw, double* __restrict__ ks_part,
    int* __restrict__ kc_part,
    const float* __restrict__ x, const float* __restrict__ gamma,
    const float* __restrict__ beta, const float* __restrict__ mu_arr,
    const float* __restrict__ rstd_arr,
    const float* __restrict__ amax_part, signed char* __restrict__ qx) {
  int t = threadIdx.x;
  int wave = t >> 6, lane = t & 63;

  if (blockIdx.x < 256) {
    // Fixed-order reduce of wsum_part[256]: identical value in every block.
    __shared__ double lsum[4];
    __shared__ double lss[4];
    __shared__ int    lcc[4];
    double sp = wsum_part[t];
    #pragma unroll
    for (int off = 1; off < 64; off <<= 1) sp += __shfl_xor(sp, off, 64);
    if (lane == 0) lsum[wave] = sp;
    __syncthreads();
    double sumw = ((lsum[0] + lsum[1]) + lsum[2]) + lsum[3];
    double delta = 0.7 * sumw * (1.0 / (double)W_ELEMS);

    int base = blockIdx.x * 1024 + t;
    double ks = 0.0;
    int kc = 0;
    #pragma unroll
    for (int j = 0; j < 4; j++) {
      float4 v = ((const float4*)w)[base + 256 * j];
      char4 q;
      {
        double a = (double)fabsf(v.x); bool m = a > delta;
        q.x = m ? (v.x > 0.0f ? 1 : -1) : 0; if (m) { ks += a; kc++; }
      }
      {
        double a = (double)fabsf(v.y); bool m = a > delta;
        q.y = m ? (v.y > 0.0f ? 1 : -1) : 0; if (m) { ks += a; kc++; }
      }
      {
        double a = (double)fabsf(v.z); bool m = a > delta;
        q.z = m ? (v.z > 0.0f ? 1 : -1) : 0; if (m) { ks += a; kc++; }
      }
      {
        double a = (double)fabsf(v.w); bool m = a > delta;
        q.w = m ? (v.w > 0.0f ? 1 : -1) : 0; if (m) { ks += a; kc++; }
      }
      ((char4*)qw)[base + 256 * j] = q;
    }
    #pragma unroll
    for (int off = 1; off < 64; off <<= 1) {
      ks += __shfl_xor(ks, off, 64);
      kc += __shfl_xor(kc, off, 64);
    }
    if (lane == 0) { lss[wave] = ks; lcc[wave] = kc; }
    __syncthreads();
    if (t == 0) {
      ks_part[blockIdx.x] = ((lss[0] + lss[1]) + lss[2]) + lss[3];
      kc_part[blockIdx.x] = ((lcc[0] + lcc[1]) + lcc[2]) + lcc[3];
    }
  } else {
    // Reduce amax_part[1024] (max is order-free).
    __shared__ float lam[4];
    float am = fmaxf(fmaxf(amax_part[t], amax_part[t + 256]),
                     fmaxf(amax_part[t + 512], amax_part[t + 768]));
    #pragma unroll
    for (int off = 1; off < 64; off <<= 1)
      am = fmaxf(am, __shfl_xor(am, off, 64));
    if (lane == 0) lam[wave] = am;
    __syncthreads();
    am = fmaxf(fmaxf(lam[0], lam[1]), fmaxf(lam[2], lam[3]));
    float scale = fmaxf(am, 1e-8f) / 127.0f;

    float4 g = ((const float4*)gamma)[t];
    float4 b = ((const float4*)beta)[t];
    int bid2 = blockIdx.x - 256;
    #pragma unroll 2
    for (int i = 0; i < 16; i++) {
      int row = bid2 * 16 + i;
      float mu = mu_arr[row], rstd = rstd_arr[row];
      float4 v = ((const float4*)(x + (size_t)row * D_IN))[t];
      float nx = ((v.x - mu) * rstd * g.x + b.x) / scale;
      float ny = ((v.y - mu) * rstd * g.y + b.y) / scale;
      float nz = ((v.z - mu) * rstd * g.z + b.z) / scale;
      float nw = ((v.w - mu) * rstd * g.w + b.w) / scale;
      char4 q;
      q.x = (signed char)(int)rintf(fminf(fmaxf(nx, -127.0f), 127.0f));
      q.y = (signed char)(int)rintf(fminf(fmaxf(ny, -127.0f), 127.0f));
      q.z = (signed char)(int)rintf(fminf(fmaxf(nz, -127.0f), 127.0f));
      q.w = (signed char)(int)rintf(fminf(fmaxf(nw, -127.0f), 127.0f));
      ((char4*)(qx + (size_t)row * D_IN))[t] = q;
    }
  }
}

// ---------------- K3: int8 GEMM, 256x256 tile, 8-phase counted-vmcnt --------
// m201-style schedule: 8 waves (2M x 4N), per-wave out 128x64, BK=128 i8.
// LDS 128 KiB: A: 2buf x 2half x [128 rows][128B]; B same at +64KiB.
// st_16x32 swizzle: linear global_load_lds dest + inverse-swizzled global
// SOURCE + swizzled READ. Stage slot-reuse: a slot is restaged only after the
// phase whose end-barrier retires its last ds_read.
//   p0: B(tO)h1 + A(tO)h1        p4: A(tE+2)h1
//   p2: B(tE+2)h0                p6: B(tO+2)h0
//   p3: B(tE+2)h1 + A(tE+2)h0    p7: A(tO+2)h0
// Waits: end-p3 vmcnt(6) -> tO complete; end-p7 vmcnt(4) -> tE+2 complete.
// Never drains to 0 in the main loop.

__device__ __forceinline__ void stage16(const signed char* src, signed char* dst) {
  __builtin_amdgcn_global_load_lds(
      (const __attribute__((address_space(1))) unsigned int*)src,
      (__attribute__((address_space(3))) unsigned int*)dst, 16, 0, 0);
}

#define BAR()   __builtin_amdgcn_s_barrier()
#define BARS()  { __builtin_amdgcn_s_barrier(); __builtin_amdgcn_sched_barrier(0); }
#define LGKM0() { asm volatile("s_waitcnt lgkmcnt(0)" ::: "memory"); __builtin_amdgcn_sched_barrier(0); }
#define VMW(N)  { asm volatile("s_waitcnt vmcnt(" #N ")" ::: "memory"); __builtin_amdgcn_sched_barrier(0); }

#define STAGE_A(BUF, HALF, KB) { \
  signed char* d_ = ldsA + (((BUF)*2 + (HALF)) << 14) + (tid << 4); \
  const signed char* s_ = Asrc + (size_t)(HALF) * (128 * D_IN) + (KB); \
  stage16(s_, d_); stage16(s_ + 64 * D_IN, d_ + 8192); }

#define STAGE_B(BUF, HALF, KB) { \
  signed char* d_ = ldsB + (((BUF)*2 + (HALF)) << 14) + (tid << 4); \
  const signed char* s_ = Bsrc + (size_t)(HALF) * (128 * D_IN) + (KB); \
  stage16(s_, d_); stage16(s_ + 64 * D_IN, d_ + 8192); }

#define LOAD_A(P, RH) { _Pragma("unroll") \
  for (int f_ = 0; f_ < 4; f_++) { \
    const signed char* rp_ = (P) + (((RH)*64 + f_*16 + lrow) << 7); \
    a[f_][0] = *(const int4v*)(rp_ + kA0); \
    a[f_][1] = *(const int4v*)(rp_ + kA1); } }

#define LOAD_B(P, CH) { _Pragma("unroll") \
  for (int g_ = 0; g_ < 2; g_++) { \
    const signed char* rp_ = (P) + ((bro + (CH)*32 + g_*16 + lrow) << 7); \
    b[CH][g_][0] = *(const int4v*)(rp_ + kA0); \
    b[CH][g_][1] = *(const int4v*)(rp_ + kA1); } }

#define MFMA_Q(RH, CH) { _Pragma("unroll") \
  for (int f_ = 0; f_ < 4; f_++) { _Pragma("unroll") \
    for (int g_ = 0; g_ < 2; g_++) { \
      acc[(RH)*4+f_][(CH)*2+g_] = __builtin_amdgcn_mfma_i32_16x16x64_i8( \
          a[f_][0], b[CH][g_][0], acc[(RH)*4+f_][(CH)*2+g_], 0, 0, 0); \
      acc[(RH)*4+f_][(CH)*2+g_] = __builtin_amdgcn_mfma_i32_16x16x64_i8( \
          a[f_][1], b[CH][g_][1], acc[(RH)*4+f_][(CH)*2+g_], 0, 0, 0); } } }

#define KITER(FULL, koO, koE2, koO2) \
  /* p0: Q0 of tE */ \
  LOAD_A(pA0, 0); LOAD_B(pB0, 0); \
  STAGE_B(1, 1, koO); STAGE_A(1, 1, koO); \
  asm volatile("s_waitcnt lgkmcnt(8)" ::: "memory"); \
  BAR(); LGKM0(); \
  __builtin_amdgcn_s_setprio(1); MFMA_Q(0, 0); __builtin_amdgcn_s_setprio(0); BARS(); \
  /* p1: Q1 of tE */ \
  LOAD_B(pB0, 1); BAR(); LGKM0(); \
  __builtin_amdgcn_s_setprio(1); MFMA_Q(0, 1); __builtin_amdgcn_s_setprio(0); BARS(); \
  /* p2: Q2 of tE */ \
  LOAD_A(pA0, 1); if (FULL) { STAGE_B(0, 0, koE2); } BAR(); LGKM0(); \
  __builtin_amdgcn_s_setprio(1); MFMA_Q(1, 0); __builtin_amdgcn_s_setprio(0); BARS(); \
  /* p3: Q3 of tE (reg-only) */ \
  if (FULL) { STAGE_B(0, 1, koE2); STAGE_A(0, 0, koE2); } BAR(); \
  __builtin_amdgcn_s_setprio(1); MFMA_Q(1, 1); __builtin_amdgcn_s_setprio(0); \
  if (FULL) { VMW(6); } else { VMW(0); } BARS(); \
  /* p4: Q0 of tO */ \
  LOAD_A(pA1, 0); LOAD_B(pB1, 0); if (FULL) { STAGE_A(0, 1, koE2); } \
  asm volatile("s_waitcnt lgkmcnt(8)" ::: "memory"); \
  BAR(); LGKM0(); \
  __builtin_amdgcn_s_setprio(1); MFMA_Q(0, 0); __builtin_amdgcn_s_setprio(0); BARS(); \
  /* p5: Q1 of tO */ \
  LOAD_B(pB1, 1); BAR(); LGKM0(); \
  __builtin_amdgcn_s_setprio(1); MFMA_Q(0, 1); __builtin_amdgcn_s_setprio(0); BARS(); \
  /* p6: Q2 of tO */ \
  LOAD_A(pA1, 1); if (FULL) { STAGE_B(1, 0, koO2); } BAR(); LGKM0(); \
  __builtin_amdgcn_s_setprio(1); MFMA_Q(1, 0); __builtin_amdgcn_s_setprio(0); BARS(); \
  /* p7: Q3 of tO (reg-only) */ \
  if (FULL) { STAGE_A(1, 0, koO2); } BAR(); \
  __builtin_amdgcn_s_setprio(1); MFMA_Q(1, 1); __builtin_amdgcn_s_setprio(0); \
  if (FULL) { VMW(4); } BARS();

__global__ __launch_bounds__(512, 2) void gemm_i8_256_kernel(
    const signed char* __restrict__ A,   // qx [32768][1024]
    const signed char* __restrict__ B,   // qw [1024][1024] (row = out feature)
    float* __restrict__ C,               // [32768][1024]
    const float* __restrict__ amax_part,
    const double* __restrict__ ks_part, const int* __restrict__ kc_part) {
  extern __shared__ __align__(16) signed char lds[];   // 131072 B
  signed char* ldsA = lds;
  signed char* ldsB = lds + 65536;

  const int tid = threadIdx.x;          // 0..511
  const int lane = tid & 63;
  const int wid = tid >> 6;             // 0..7
  const int wr = wid >> 2;              // 0..1 (M)
  const int wc = wid & 3;               // 0..3 (N)

  // XCD-aware bijective swizzle (nwg=512, 512%8==0)
  int wg = ((blockIdx.x & 7) << 6) + (blockIdx.x >> 3);
  const int m0 = (wg >> 2) << 8;        // 128 m-blocks
  const int n0 = (wg & 3) << 8;         // 4 n-blocks

  // ---- Fixed-order scalar reduction (identical value in every block). ----
  // Uses the LDS staging area BEFORE any global_load_lds is issued; a full
  // drain afterwards keeps the pipelined loop's vmcnt counting exact.
  float fscale;
  {
    double* lred = (double*)lds;        // 8 x f64
    float*  lam  = (float*)(lds + 64);  // 8 x f32
    int*    lkc  = (int*)(lds + 96);    // 8 x i32
    float amv = fmaxf(amax_part[tid], amax_part[tid + 512]);
    double ksv = (tid < 256) ? ks_part[tid] : 0.0;
    int    kcv = (tid < 256) ? kc_part[tid] : 0;
    #pragma unroll
    for (int off = 1; off < 64; off <<= 1) {
      amv = fmaxf(amv, __shfl_xor(amv, off, 64));
      ksv += __shfl_xor(ksv, off, 64);
      kcv += __shfl_xor(kcv, off, 64);
    }
    if (lane == 0) { lred[wid] = ksv; lam[wid] = amv; lkc[wid] = kcv; }
    __syncthreads();
    double ksum = 0.0; int kcnt = 0; float am = 0.0f;
    for (int wv = 0; wv < 8; wv++) {    // serial fixed order (no reassoc)
      ksum += lred[wv]; kcnt += lkc[wv]; am = fmaxf(am, lam[wv]);
    }
    double alpha = ksum / (double)((kcnt > 1) ? kcnt : 1);
    fscale = (float)(((double)fmaxf(am, 1e-8f) / 127.0) * alpha);
    __syncthreads();                    // all readers done before staging
  }
  asm volatile("s_waitcnt vmcnt(0) lgkmcnt(0)" ::: "memory");
  __builtin_amdgcn_sched_barrier(0);

  // Staging geometry: linear LDS dest (o = tid*16, +8192), source address
  // pre-swizzled with the same involution the reads apply.
  int so = (tid << 4) ^ (((tid >> 5) & 1) << 5);
  int r0 = so >> 7, c0 = so & 127;
  const signed char* Asrc = A + (size_t)(m0 + r0) * D_IN + c0;
  const signed char* Bsrc = B + (size_t)(n0 + r0) * D_IN + c0;

  // Read geometry: lane holds A/B row (lane&15), 16B k-chunk (lane>>4).
  const int lrow = lane & 15;
  const int kA0 = ((lane >> 4) << 4) ^ (((lrow >> 2) & 1) << 5);
  const int kA1 = 64 + kA0;
  const int bro = (wc & 1) << 6;        // B row base within its half
  const signed char* pA0 = ldsA + (wr << 14);          // buf0, A half = wr
  const signed char* pA1 = pA0 + 32768;                // buf1
  const signed char* pB0 = ldsB + ((wc >> 1) << 14);   // buf0, B half = wc>>1
  const signed char* pB1 = pB0 + 32768;                // buf1

  int4v acc[8][4] = {};
  int4v a[4][2];
  int4v b[2][2][2];

  // Prologue: tile0 complete (4 halves) + tile1 h0s; leave 4 loads in flight.
  STAGE_B(0, 0, 0); STAGE_B(0, 1, 0);
  STAGE_A(0, 0, 0); STAGE_A(0, 1, 0);
  STAGE_B(1, 0, 128); STAGE_A(1, 0, 128);
  VMW(4); BARS();

  for (int i = 0; i < 3; i++) {
    int koO  = (2 * i + 1) * 128;
    int koE2 = (2 * i + 2) * 128;
    int koO2 = (2 * i + 3) * 128;
    KITER(1, koO, koE2, koO2)
  }
  { // tail: tiles 6,7; only p0 stages (tile7 h1s); drain fully at end-p3.
    int koO = 7 * 128;
    KITER(0, koO, 0, 0)
  }

  // Epilogue: plain coalescing stores (nt stores regressed in R3).
  const int crow0 = m0 + (wr << 7) + ((lane >> 4) << 2);
  const int ccol0 = n0 + (wc << 6) + (lane & 15);
  #pragma unroll
  for (int rf = 0; rf < 8; rf++)
    #pragma unroll
    for (int cf = 0; cf < 4; cf++)
      #pragma unroll
      for (int rr = 0; rr < 4; rr++) {
        int row = crow0 + rf * 16 + rr;
        C[(size_t)row * D_OUT + ccol0 + cf * 16] = (float)acc[rf][cf][rr] * fscale;
      }
}

extern "C" void kernel_launch(void* const* d_in, const int* in_sizes, int n_in,
                              void* d_out, int out_size, void* d_ws, size_t ws_size,
                              hipStream_t stream) {
  const float* x     = (const float*)d_in[0];
  const float* w     = (const float*)d_in[1];
  const float* gamma = (const float*)d_in[2];
  const float* beta  = (const float*)d_in[3];
  float* out = (float*)d_out;

  char* ws = (char*)d_ws;
  double* wsum_part = (double*)(ws + 256);
  float*  amax_part = (float*)(ws + 4096);
  double* ks_part   = (double*)(ws + 8192);
  int*    kc_part   = (int*)(ws + 10240);
  float* mu   = (float*)(ws + 16384);
  float* rstd = (float*)(ws + 147456);
  signed char* qw = (signed char*)(ws + 278528);
  signed char* qx = (signed char*)(ws + 1327104);

  ln_stats_wsum_kernel<<<1280, 256, 0, stream>>>(x, gamma, beta, mu, rstd,
                                                 amax_part, w, wsum_part);
  wquant_actquant_kernel<<<2304, 256, 0, stream>>>(w, wsum_part, qw, ks_part,
                                                   kc_part, x, gamma, beta, mu,
                                                   rstd, amax_part, qx);
  gemm_i8_256_kernel<<<512, 512, 131072, stream>>>(qx, qw, out, amax_part,
                                                   ks_part, kc_part);
}